// Round 1
// baseline (204.243 us; speedup 1.0000x reference)
//
#include <hip/hip_runtime.h>

// LinearCRF: mean_b( logZ_b - gold_b ), B=8192, L=1024, S=3.
// Strategy: scaled (linear-domain) forward algorithm. Each lane owns a
// 16-step chunk and builds the 3x3 transfer-matrix product in linear space
// (renormalized by exact power-of-2 scaling via frexp/ldexp); a 6-stage
// ordered shfl_xor butterfly composes the 64 chunk matrices per wave
// (1 wave == 1 sequence). Gold score fused in the same pass.
// All scores scaled by log2(e) so v_exp_f32 / v_log_f32 are used natively.

#define LOG2E 1.4426950408889634f
#define LN2   0.6931471805599453f

constexpr int B = 8192;
constexpr int L = 1024;
constexpr int S = 3;
constexpr int CHUNK = 16;           // timesteps per lane
constexpr int SEQS_PER_BLOCK = 4;   // 4 waves of 64 per block

__device__ __forceinline__ float fast_exp2(float x) { return __builtin_amdgcn_exp2f(x); }
__device__ __forceinline__ float fast_log2(float x) { return __builtin_amdgcn_logf(x); }

__device__ __forceinline__ void matmul3(float* __restrict__ D,
                                        const float* __restrict__ A,
                                        const float* __restrict__ Bm) {
  #pragma unroll
  for (int i = 0; i < 3; ++i)
    #pragma unroll
    for (int j = 0; j < 3; ++j)
      D[i * 3 + j] = A[i * 3 + 0] * Bm[0 * 3 + j] +
                     A[i * 3 + 1] * Bm[1 * 3 + j] +
                     A[i * 3 + 2] * Bm[2 * 3 + j];
}

// Exact power-of-2 renormalization: P *= 2^-ex, scale += ex (no transcendentals).
__device__ __forceinline__ void renorm3(float* __restrict__ P, float& scale) {
  float m = P[0];
  #pragma unroll
  for (int e = 1; e < 9; ++e) m = fmaxf(m, P[e]);
  int ex;
  (void)frexpf(m, &ex);
  #pragma unroll
  for (int e = 0; e < 9; ++e) P[e] = ldexpf(P[e], -ex);
  scale += (float)ex;
}

__global__ __launch_bounds__(256) void crf_main(
    const float* __restrict__ em, const float* __restrict__ mask,
    const float* __restrict__ trans, const int* __restrict__ tags,
    float* __restrict__ ws) {
  const int lane = threadIdx.x & 63;
  const int b = blockIdx.x * SEQS_PER_BLOCK + (threadIdx.x >> 6);

  // Transitions in log2 domain + their linear form.
  float T2[9], tk[9];
  #pragma unroll
  for (int e = 0; e < 9; ++e) {
    T2[e] = trans[e] * LOG2E;
    tk[e] = fast_exp2(T2[e]);
  }

  // ---- load this lane's 16-step chunk (all 16B-aligned vector loads) ----
  const float4* em4 = (const float4*)(em + (size_t)b * (L * S));
  float ev[CHUNK * 3];
  #pragma unroll
  for (int u = 0; u < 12; ++u) {
    float4 v = em4[lane * 12 + u];
    ev[4 * u + 0] = v.x * LOG2E;
    ev[4 * u + 1] = v.y * LOG2E;
    ev[4 * u + 2] = v.z * LOG2E;
    ev[4 * u + 3] = v.w * LOG2E;
  }
  const float4* mk4 = (const float4*)(mask + (size_t)b * L);
  float mk[CHUNK];
  #pragma unroll
  for (int u = 0; u < 4; ++u) {
    float4 v = mk4[lane * 4 + u];
    mk[4 * u + 0] = v.x; mk[4 * u + 1] = v.y;
    mk[4 * u + 2] = v.z; mk[4 * u + 3] = v.w;
  }
  const int4* tg4 = (const int4*)(tags + (size_t)b * L);
  int tg[CHUNK];
  #pragma unroll
  for (int u = 0; u < 4; ++u) {
    int4 v = tg4[lane * 4 + u];
    tg[4 * u + 0] = v.x; tg[4 * u + 1] = v.y;
    tg[4 * u + 2] = v.z; tg[4 * u + 3] = v.w;
  }

  // ---- gold score partial (log2-scaled domain) ----
  int prev = __shfl_up(tg[CHUNK - 1], 1);  // tag[t0-1] from previous lane
  float gold = 0.f;
  #pragma unroll
  for (int s = 0; s < CHUNK; ++s) {
    const int cur = tg[s];
    const float e = (cur == 0) ? ev[s * 3 + 0]
                   : ((cur == 1) ? ev[s * 3 + 1] : ev[s * 3 + 2]);
    if (s == 0 && lane == 0) {
      gold = e * mk[0];                      // t=0: emission only
    } else {
      const float r0 = (cur == 0) ? T2[0] : ((cur == 1) ? T2[1] : T2[2]);
      const float r1 = (cur == 0) ? T2[3] : ((cur == 1) ? T2[4] : T2[5]);
      const float r2 = (cur == 0) ? T2[6] : ((cur == 1) ? T2[7] : T2[8]);
      const float tr = (prev == 0) ? r0 : ((prev == 1) ? r1 : r2);
      gold += (tr + e) * mk[s];
    }
    prev = cur;
  }
  #pragma unroll
  for (int d = 1; d < 64; d <<= 1) gold += __shfl_xor(gold, d, 64);

  // ---- per-lane chunk matrix product, linear domain ----
  float P[9] = {1.f, 0.f, 0.f, 0.f, 1.f, 0.f, 0.f, 0.f, 1.f};
  float scale = 0.f;
  #pragma unroll
  for (int s = 0; s < CHUNK; ++s) {
    const bool doStep = (mk[s] > 0.f) && !(s == 0 && lane == 0);  // t=0 is alpha0
    if (doStep) {
      const float w0 = fast_exp2(ev[s * 3 + 0]);
      const float w1 = fast_exp2(ev[s * 3 + 1]);
      const float w2 = fast_exp2(ev[s * 3 + 2]);
      float M[9] = {tk[0] * w0, tk[1] * w1, tk[2] * w2,
                    tk[3] * w0, tk[4] * w1, tk[5] * w2,
                    tk[6] * w0, tk[7] * w1, tk[8] * w2};
      float N[9];
      matmul3(N, P, M);
      #pragma unroll
      for (int e = 0; e < 9; ++e) P[e] = N[e];
    }
    if (s == 7) renorm3(P, scale);  // bound fp32 range mid-chunk
  }
  renorm3(P, scale);

  // ---- ordered butterfly combine across the wave (64 chunks -> product) ----
  #pragma unroll
  for (int d = 1; d < 64; d <<= 1) {
    float o[9];
    #pragma unroll
    for (int e = 0; e < 9; ++e) o[e] = __shfl_xor(P[e], d, 64);
    const float osc = __shfl_xor(scale, d, 64);
    const bool later = (lane & d) != 0;  // self covers the later segment
    float A[9], Bm[9];
    #pragma unroll
    for (int e = 0; e < 9; ++e) {
      A[e]  = later ? o[e] : P[e];
      Bm[e] = later ? P[e] : o[e];
    }
    float N[9];
    matmul3(N, A, Bm);
    #pragma unroll
    for (int e = 0; e < 9; ++e) P[e] = N[e];
    scale += osc;
    renorm3(P, scale);
  }

  // ---- finalize: logZ = scale + log2( alpha0_lin . P . 1 ) ----
  if (lane == 0) {
    const float a0 = fast_exp2(ev[0]);
    const float a1 = fast_exp2(ev[1]);
    const float a2 = fast_exp2(ev[2]);
    const float z = a0 * (P[0] + P[1] + P[2]) +
                    a1 * (P[3] + P[4] + P[5]) +
                    a2 * (P[6] + P[7] + P[8]);
    const float logZ2 = scale + fast_log2(z);
    ws[b] = LN2 * (logZ2 - gold);
  }
}

__global__ __launch_bounds__(256) void crf_reduce(const float* __restrict__ ws,
                                                  float* __restrict__ out) {
  __shared__ float red[4];
  const int tid = threadIdx.x;
  float s = 0.f;
  for (int i = tid; i < B; i += 256) s += ws[i];
  #pragma unroll
  for (int d = 1; d < 64; d <<= 1) s += __shfl_xor(s, d, 64);
  if ((tid & 63) == 0) red[tid >> 6] = s;
  __syncthreads();
  if (tid == 0) out[0] = (red[0] + red[1] + red[2] + red[3]) * (1.0f / (float)B);
}

extern "C" void kernel_launch(void* const* d_in, const int* in_sizes, int n_in,
                              void* d_out, int out_size, void* d_ws, size_t ws_size,
                              hipStream_t stream) {
  const float* em    = (const float*)d_in[0];
  const float* mask  = (const float*)d_in[1];
  const float* trans = (const float*)d_in[2];
  const int*   tags  = (const int*)d_in[3];
  float* ws  = (float*)d_ws;   // 8192 floats of per-sequence (logZ - gold)
  float* out = (float*)d_out;

  crf_main<<<B / SEQS_PER_BLOCK, 256, 0, stream>>>(em, mask, trans, tags, ws);
  crf_reduce<<<1, 256, 0, stream>>>(ws, out);
}

// Round 2
// 197.177 us; speedup vs baseline: 1.0358x; 1.0358x over previous
//
#include <hip/hip_runtime.h>

// LinearCRF: mean_b( logZ_b - gold_b ), B=8192, L=1024, S=3.
// Scaled linear-domain forward: lane owns a 16-step chunk, builds the 3x3
// transfer-matrix product in linear space with exact power-of-2 renorm
// (frexp/ldexp); 6-stage ordered shfl_xor butterfly composes 64 chunks per
// wave (1 wave = 1 sequence). Gold score fused. Loads fused with compute in
// 4-step groups to keep the live set in registers (R1 spilled: VGPR=60 with
// 80 live floats -> 65 MB scratch writes).
// Block reduce + atomicAdd replaces the second kernel.

#define LOG2E 1.4426950408889634f
#define LN2   0.6931471805599453f

constexpr int B = 8192;
constexpr int L = 1024;
constexpr int SEQS_PER_BLOCK = 4;   // 4 waves of 64 per block

__device__ __forceinline__ float fexp2(float x) { return __builtin_amdgcn_exp2f(x); }
__device__ __forceinline__ float flog2(float x) { return __builtin_amdgcn_logf(x); }

__device__ __forceinline__ float mux3(float x0, float x1, float x2, int i) {
  return (i == 0) ? x0 : ((i == 1) ? x1 : x2);
}
// transitions[p][c] via cndmask chain (no dynamic register indexing -> no scratch)
__device__ __forceinline__ float trmux(const float* __restrict__ T2, int p, int c) {
  const float r0 = mux3(T2[0], T2[1], T2[2], c);
  const float r1 = mux3(T2[3], T2[4], T2[5], c);
  const float r2 = mux3(T2[6], T2[7], T2[8], c);
  return mux3(r0, r1, r2, p);
}

__device__ __forceinline__ void matmul3(float* __restrict__ D,
                                        const float* __restrict__ A,
                                        const float* __restrict__ Bm) {
  #pragma unroll
  for (int i = 0; i < 3; ++i)
    #pragma unroll
    for (int j = 0; j < 3; ++j)
      D[i * 3 + j] = A[i * 3 + 0] * Bm[0 * 3 + j] +
                     A[i * 3 + 1] * Bm[1 * 3 + j] +
                     A[i * 3 + 2] * Bm[2 * 3 + j];
}

// Exact power-of-2 renormalization: P *= 2^-ex, scale += ex.
__device__ __forceinline__ void renorm3(float* __restrict__ P, float& scale) {
  float m = P[0];
  #pragma unroll
  for (int e = 1; e < 9; ++e) m = fmaxf(m, P[e]);
  int ex;
  (void)frexpf(m, &ex);
  #pragma unroll
  for (int e = 0; e < 9; ++e) P[e] = ldexpf(P[e], -ex);
  scale += (float)ex;
}

__global__ __launch_bounds__(256, 4) void crf_main(
    const float* __restrict__ em, const float* __restrict__ mask,
    const float* __restrict__ trans, const int* __restrict__ tags,
    float* __restrict__ out) {
  const int lane = threadIdx.x & 63;
  const int wid = threadIdx.x >> 6;
  const int b = blockIdx.x * SEQS_PER_BLOCK + wid;

  // Transitions: log2 domain + linear form.
  float T2[9], tk[9];
  #pragma unroll
  for (int e = 0; e < 9; ++e) {
    T2[e] = trans[e] * LOG2E;
    tk[e] = fexp2(T2[e]);
  }

  const float4* em4 = (const float4*)(em + (size_t)b * (L * 3));
  const float4* mk4 = (const float4*)(mask + (size_t)b * L);
  const int4*   tg4 = (const int4*)(tags + (size_t)b * L);

  float P[9] = {1.f, 0.f, 0.f, 0.f, 1.f, 0.f, 0.f, 0.f, 1.f};
  float scale = 0.f, gold = 0.f;
  float a0 = 0.f, a1 = 0.f, a2 = 0.f;       // step-0 linear emissions (lane 0 uses)
  float e0_sel = 0.f, mk0 = 0.f;            // deferred step-0 gold term
  int tag0 = 0, prev = 0;

  #pragma unroll
  for (int g = 0; g < 4; ++g) {
    // 4 timesteps per group: 3 em float4 + 1 mask float4 + 1 tag int4.
    const float4 x0 = em4[lane * 12 + 3 * g + 0];
    const float4 x1 = em4[lane * 12 + 3 * g + 1];
    const float4 x2 = em4[lane * 12 + 3 * g + 2];
    const float4 mm = mk4[lane * 4 + g];
    const int4   tt = tg4[lane * 4 + g];
    const float ef[12] = {x0.x, x0.y, x0.z, x0.w, x1.x, x1.y, x1.z, x1.w,
                          x2.x, x2.y, x2.z, x2.w};
    const float mf[4] = {mm.x, mm.y, mm.z, mm.w};
    const int   tf[4] = {tt.x, tt.y, tt.z, tt.w};

    #pragma unroll
    for (int j = 0; j < 4; ++j) {
      const int s = 4 * g + j;
      const float ev0 = ef[3 * j + 0] * LOG2E;
      const float ev1 = ef[3 * j + 1] * LOG2E;
      const float ev2 = ef[3 * j + 2] * LOG2E;
      const float m = mf[j];
      const int cur = tf[j];

      // ---- gold score (log2 domain) ----
      const float e = mux3(ev0, ev1, ev2, cur);
      if (s == 0) {
        e0_sel = e; mk0 = m; tag0 = cur;   // cross-lane prev tag: fix up later
      } else {
        gold = fmaf(trmux(T2, prev, cur) + e, m, gold);
      }
      prev = cur;

      // ---- matrix step (linear domain) ----
      const float w0 = fexp2(ev0);
      const float w1 = fexp2(ev1);
      const float w2 = fexp2(ev2);
      if (s == 0) { a0 = w0; a1 = w1; a2 = w2; }
      const bool act = (m > 0.f) && !(s == 0 && lane == 0);  // t=0 is alpha0
      const float M[9] = {tk[0] * w0, tk[1] * w1, tk[2] * w2,
                          tk[3] * w0, tk[4] * w1, tk[5] * w2,
                          tk[6] * w0, tk[7] * w1, tk[8] * w2};
      float N[9];
      matmul3(N, P, M);
      #pragma unroll
      for (int e2 = 0; e2 < 9; ++e2) P[e2] = act ? N[e2] : P[e2];

      if (s == 7 || s == 15) renorm3(P, scale);  // bound fp32 range
    }
  }

  // ---- deferred step-0 gold term (needs previous lane's last tag) ----
  const int prevLast = __shfl_up(prev, 1);
  if (lane == 0) gold = fmaf(e0_sel, mk0, gold);
  else           gold = fmaf(trmux(T2, prevLast, tag0) + e0_sel, mk0, gold);
  #pragma unroll
  for (int d = 1; d < 64; d <<= 1) gold += __shfl_xor(gold, d, 64);

  // ---- ordered butterfly combine (entries <= 3^6 = 729: no renorm needed) ----
  #pragma unroll
  for (int d = 1; d < 64; d <<= 1) {
    float o[9];
    #pragma unroll
    for (int e = 0; e < 9; ++e) o[e] = __shfl_xor(P[e], d, 64);
    const float osc = __shfl_xor(scale, d, 64);
    const bool later = (lane & d) != 0;  // self covers the later time segment
    float A[9], Bm[9];
    #pragma unroll
    for (int e = 0; e < 9; ++e) {
      A[e]  = later ? o[e] : P[e];
      Bm[e] = later ? P[e] : o[e];
    }
    float N[9];
    matmul3(N, A, Bm);
    #pragma unroll
    for (int e = 0; e < 9; ++e) P[e] = N[e];
    scale += osc;
  }

  // ---- finalize + block reduce + atomic ----
  __shared__ float red[SEQS_PER_BLOCK];
  if (lane == 0) {
    const float z = a0 * (P[0] + P[1] + P[2]) +
                    a1 * (P[3] + P[4] + P[5]) +
                    a2 * (P[6] + P[7] + P[8]);
    red[wid] = LN2 * (scale + flog2(z) - gold);
  }
  __syncthreads();
  if (threadIdx.x == 0) {
    const float s = red[0] + red[1] + red[2] + red[3];
    atomicAdd(out, s * (1.0f / (float)B));
  }
}

extern "C" void kernel_launch(void* const* d_in, const int* in_sizes, int n_in,
                              void* d_out, int out_size, void* d_ws, size_t ws_size,
                              hipStream_t stream) {
  const float* em    = (const float*)d_in[0];
  const float* mask  = (const float*)d_in[1];
  const float* trans = (const float*)d_in[2];
  const int*   tags  = (const int*)d_in[3];
  float* out = (float*)d_out;

  hipMemsetAsync(out, 0, sizeof(float), stream);  // atomic accumulator init
  crf_main<<<B / SEQS_PER_BLOCK, 256, 0, stream>>>(em, mask, trans, tags, out);
}

// Round 3
// 196.254 us; speedup vs baseline: 1.0407x; 1.0047x over previous
//
#include <hip/hip_runtime.h>

// LinearCRF: mean_b( logZ_b - gold_b ), B=8192, L=1024, S=3.
// Scaled linear-domain forward: lane owns a 16-step chunk, builds the 3x3
// transfer-matrix product in linear space with exact power-of-2 renorm;
// 6-stage ordered shfl_xor butterfly composes 64 chunks per wave
// (1 wave = 1 sequence). Gold score fused.
// R3: ALL 20 vector loads hoisted to one up-front burst (R2's group-fused
// loop serialized 4 memory round-trips per wave at VGPR=60 -> latency-bound,
// VALUBusy 28%). launch_bounds(256,4) caps VGPR at 128 so the burst fits.
// Step matrix built as (act ? tk*w : I) and multiplied unconditionally
// (P*I exact) -- removes 9 cndmask/step result-select.

#define LOG2E 1.4426950408889634f
#define LN2   0.6931471805599453f

constexpr int B = 8192;
constexpr int L = 1024;
constexpr int SEQS_PER_BLOCK = 4;   // 4 waves of 64 per block

__device__ __forceinline__ float fexp2(float x) { return __builtin_amdgcn_exp2f(x); }
__device__ __forceinline__ float flog2(float x) { return __builtin_amdgcn_logf(x); }

__device__ __forceinline__ float f4get(const float4& v, int c) {
  return c == 0 ? v.x : (c == 1 ? v.y : (c == 2 ? v.z : v.w));
}
__device__ __forceinline__ int i4get(const int4& v, int c) {
  return c == 0 ? v.x : (c == 1 ? v.y : (c == 2 ? v.z : v.w));
}

__device__ __forceinline__ float mux3(float x0, float x1, float x2, int i) {
  return (i == 0) ? x0 : ((i == 1) ? x1 : x2);
}
// transitions[p][c] via cndmask chain (no dynamic register indexing)
__device__ __forceinline__ float trmux(const float* __restrict__ T2, int p, int c) {
  const float r0 = mux3(T2[0], T2[1], T2[2], c);
  const float r1 = mux3(T2[3], T2[4], T2[5], c);
  const float r2 = mux3(T2[6], T2[7], T2[8], c);
  return mux3(r0, r1, r2, p);
}

__device__ __forceinline__ void matmul3(float* __restrict__ D,
                                        const float* __restrict__ A,
                                        const float* __restrict__ Bm) {
  #pragma unroll
  for (int i = 0; i < 3; ++i)
    #pragma unroll
    for (int j = 0; j < 3; ++j)
      D[i * 3 + j] = A[i * 3 + 0] * Bm[0 * 3 + j] +
                     A[i * 3 + 1] * Bm[1 * 3 + j] +
                     A[i * 3 + 2] * Bm[2 * 3 + j];
}

// Exact power-of-2 renormalization: P *= 2^-ex, scale += ex.
__device__ __forceinline__ void renorm3(float* __restrict__ P, float& scale) {
  float m = P[0];
  #pragma unroll
  for (int e = 1; e < 9; ++e) m = fmaxf(m, P[e]);
  int ex;
  (void)frexpf(m, &ex);
  #pragma unroll
  for (int e = 0; e < 9; ++e) P[e] = ldexpf(P[e], -ex);
  scale += (float)ex;
}

__global__ __launch_bounds__(256, 4) void crf_main(
    const float* __restrict__ em, const float* __restrict__ mask,
    const float* __restrict__ trans, const int* __restrict__ tags,
    float* __restrict__ out) {
  const int lane = threadIdx.x & 63;
  const int wid = threadIdx.x >> 6;
  const int b = blockIdx.x * SEQS_PER_BLOCK + wid;

  const float4* em4 = (const float4*)(em + (size_t)b * (L * 3)) + lane * 12;
  const float4* mk4 = (const float4*)(mask + (size_t)b * L) + lane * 4;
  const int4*   tg4 = (const int4*)(tags + (size_t)b * L) + lane * 4;

  // ---- issue ALL global loads up front: ONE latency burst per wave ----
  float4 E[12];
  #pragma unroll
  for (int u = 0; u < 12; ++u) E[u] = em4[u];
  float4 MK[4];
  #pragma unroll
  for (int u = 0; u < 4; ++u) MK[u] = mk4[u];
  int4 TG[4];
  #pragma unroll
  for (int u = 0; u < 4; ++u) TG[u] = tg4[u];

  // Transitions: log2 domain + linear form (uniform -> scalar loads).
  float T2[9], tk[9];
  #pragma unroll
  for (int e = 0; e < 9; ++e) {
    T2[e] = trans[e] * LOG2E;
    tk[e] = fexp2(T2[e]);
  }

  float P[9] = {1.f, 0.f, 0.f, 0.f, 1.f, 0.f, 0.f, 0.f, 1.f};
  float scale = 0.f, gold = 0.f;
  float a0 = 0.f, a1 = 0.f, a2 = 0.f;   // step-0 linear emissions (lane 0)
  float e0_sel = 0.f, mk0 = 0.f;        // deferred step-0 gold term
  int tag0 = 0, prev = 0;

  #pragma unroll
  for (int s = 0; s < 16; ++s) {
    const float ev0 = f4get(E[(3 * s + 0) >> 2], (3 * s + 0) & 3) * LOG2E;
    const float ev1 = f4get(E[(3 * s + 1) >> 2], (3 * s + 1) & 3) * LOG2E;
    const float ev2 = f4get(E[(3 * s + 2) >> 2], (3 * s + 2) & 3) * LOG2E;
    const float m   = f4get(MK[s >> 2], s & 3);
    const int   cur = i4get(TG[s >> 2], s & 3);

    // ---- gold score (log2 domain) ----
    const float e = mux3(ev0, ev1, ev2, cur);
    if (s == 0) {
      e0_sel = e; mk0 = m; tag0 = cur;   // cross-lane prev tag fixed up later
    } else {
      gold = fmaf(trmux(T2, prev, cur) + e, m, gold);
    }
    prev = cur;

    // ---- matrix step (linear domain): M = act ? tk.*w : I ----
    const float w0 = fexp2(ev0);
    const float w1 = fexp2(ev1);
    const float w2 = fexp2(ev2);
    if (s == 0) { a0 = w0; a1 = w1; a2 = w2; }
    const bool act = (m > 0.f) && !(s == 0 && lane == 0);  // t=0 is alpha0
    const float g  = act ? 1.f : 0.f;
    const float c1 = 1.f - g;
    const float u0 = w0 * g, u1 = w1 * g, u2 = w2 * g;
    float M[9];
    M[0] = fmaf(tk[0], u0, c1); M[1] = tk[1] * u1;           M[2] = tk[2] * u2;
    M[3] = tk[3] * u0;          M[4] = fmaf(tk[4], u1, c1);  M[5] = tk[5] * u2;
    M[6] = tk[6] * u0;          M[7] = tk[7] * u1;           M[8] = fmaf(tk[8], u2, c1);
    float N[9];
    matmul3(N, P, M);
    #pragma unroll
    for (int e2 = 0; e2 < 9; ++e2) P[e2] = N[e2];

    if (s == 7 || s == 15) renorm3(P, scale);  // bound fp32 range
  }

  // ---- deferred step-0 gold term (needs previous lane's last tag) ----
  const int prevLast = __shfl_up(prev, 1);
  if (lane == 0) gold = fmaf(e0_sel, mk0, gold);
  else           gold = fmaf(trmux(T2, prevLast, tag0) + e0_sel, mk0, gold);
  #pragma unroll
  for (int d = 1; d < 64; d <<= 1) gold += __shfl_xor(gold, d, 64);

  // ---- ordered butterfly combine (entries <= 3^6 = 729: no renorm needed) ----
  #pragma unroll
  for (int d = 1; d < 64; d <<= 1) {
    float o[9];
    #pragma unroll
    for (int e = 0; e < 9; ++e) o[e] = __shfl_xor(P[e], d, 64);
    const float osc = __shfl_xor(scale, d, 64);
    const bool later = (lane & d) != 0;  // self covers the later time segment
    float A[9], Bm[9];
    #pragma unroll
    for (int e = 0; e < 9; ++e) {
      A[e]  = later ? o[e] : P[e];
      Bm[e] = later ? P[e] : o[e];
    }
    float N[9];
    matmul3(N, A, Bm);
    #pragma unroll
    for (int e = 0; e < 9; ++e) P[e] = N[e];
    scale += osc;
  }

  // ---- finalize + block reduce + atomic ----
  __shared__ float red[SEQS_PER_BLOCK];
  if (lane == 0) {
    const float z = a0 * (P[0] + P[1] + P[2]) +
                    a1 * (P[3] + P[4] + P[5]) +
                    a2 * (P[6] + P[7] + P[8]);
    red[wid] = LN2 * (scale + flog2(z) - gold);
  }
  __syncthreads();
  if (threadIdx.x == 0) {
    const float s = red[0] + red[1] + red[2] + red[3];
    atomicAdd(out, s * (1.0f / (float)B));
  }
}

extern "C" void kernel_launch(void* const* d_in, const int* in_sizes, int n_in,
                              void* d_out, int out_size, void* d_ws, size_t ws_size,
                              hipStream_t stream) {
  const float* em    = (const float*)d_in[0];
  const float* mask  = (const float*)d_in[1];
  const float* trans = (const float*)d_in[2];
  const int*   tags  = (const int*)d_in[3];
  float* out = (float*)d_out;

  hipMemsetAsync(out, 0, sizeof(float), stream);  // atomic accumulator init
  crf_main<<<B / SEQS_PER_BLOCK, 256, 0, stream>>>(em, mask, trans, tags, out);
}